// Round 1
// baseline (974.887 us; speedup 1.0000x reference)
//
#include <hip/hip_runtime.h>
#include <hip/hip_bf16.h>
#include <math.h>

#define BATCH 262144
#define KDIM 128
#define HID 256

typedef __bf16 bf16x8 __attribute__((ext_vector_type(8)));
typedef float f32x4 __attribute__((ext_vector_type(4)));

// ws layout: Wfrag (2 parts * 16 Htiles * 4 Kchunks * 512 bf16 = 65536 bf16 = 131072 B)
//            then lam (512 float: re[0:256], im[256:512])

__global__ void lru_prep(const float* __restrict__ nu_log,
                         const float* __restrict__ theta_log,
                         const float* __restrict__ B_real,
                         const float* __restrict__ B_img,
                         const float* __restrict__ gamma_log,
                         __bf16* __restrict__ Wfrag,
                         float* __restrict__ lam)
{
    int tid = blockIdx.x * 256 + threadIdx.x;   // 0..65535
    // Wfrag index bits: p<<15 | t<<11 | c<<9 | L<<3 | j  (B-operand lane order)
    int j = tid & 7;
    int L = (tid >> 3) & 63;
    int c = (tid >> 9) & 3;
    int t = (tid >> 11) & 15;
    int p = (tid >> 15) & 1;
    int h = t * 16 + (L & 15);            // n = lane&15
    int k = c * 32 + (L >> 4) * 8 + j;    // k = quad*8 + j within 32-chunk
    const float* Bm = p ? B_img : B_real;
    float w = expf(gamma_log[h]) * Bm[h * KDIM + k];
    Wfrag[tid] = (__bf16)w;
    if (tid < HID) {
        float mag = expf(-expf(nu_log[tid]));
        float th  = expf(theta_log[tid]);
        lam[tid]       = mag * cosf(th);
        lam[HID + tid] = mag * sinf(th);
    }
}

__global__ __launch_bounds__(256) void lru_main(
    const float* __restrict__ inputs,
    const float* __restrict__ h_re,
    const float* __restrict__ h_im,
    const __bf16* __restrict__ Wfrag,
    const float* __restrict__ lam,
    float* __restrict__ out)
{
    const int hs = blockIdx.x & 3;        // H-slice (64 cols): low bits -> adjacent dispatch shares A via L3
    const int m_tile = blockIdx.x >> 2;   // 64-row M tile
    const int tid = threadIdx.x;
    const int wave = tid >> 6;
    const int lane = tid & 63;

    __shared__ __align__(16) __bf16 sW[2 * 4 * 4 * 512];   // 32 KB: [p][tl][c][64 lanes * 8]

    // stage this block's W slice (both parts, 4 H-tiles, 4 K-chunks), 2048 x uint4
    {
        const uint4* g = (const uint4*)Wfrag;
        uint4* s = (uint4*)sW;
        #pragma unroll
        for (int it = 0; it < 8; ++it) {
            int ch = tid + it * 256;
            int q  = ch & 63;
            int c  = (ch >> 6) & 3;
            int tl = (ch >> 8) & 3;
            int p  = ch >> 10;
            s[ch] = g[((p * 16 + hs * 4 + tl) * 4 + c) * 64 + q];
        }
    }

    // A fragments from global (independent of LDS, issued before barrier)
    // A layout for 16x16x32: A[m = lane&15][k = quad*8 + j]
    const int m0 = m_tile * 64 + wave * 16;
    const float* arow = inputs + (size_t)(m0 + (lane & 15)) * KDIM + ((lane >> 4) * 8);
    bf16x8 afrag[4];
    #pragma unroll
    for (int c = 0; c < 4; ++c) {
        f32x4 lo = *(const f32x4*)(arow + c * 32);
        f32x4 hi = *(const f32x4*)(arow + c * 32 + 4);
        bf16x8 a;
        a[0] = (__bf16)lo[0]; a[1] = (__bf16)lo[1];
        a[2] = (__bf16)lo[2]; a[3] = (__bf16)lo[3];
        a[4] = (__bf16)hi[0]; a[5] = (__bf16)hi[1];
        a[6] = (__bf16)hi[2]; a[7] = (__bf16)hi[3];
        afrag[c] = a;
    }

    __syncthreads();

    f32x4 accRe[4], accIm[4];
    #pragma unroll
    for (int tl = 0; tl < 4; ++tl) {
        accRe[tl] = (f32x4){0.f, 0.f, 0.f, 0.f};
        accIm[tl] = (f32x4){0.f, 0.f, 0.f, 0.f};
    }

    const bf16x8* sWv = (const bf16x8*)sW;   // lane-linear ds_read_b128
    #pragma unroll
    for (int c = 0; c < 4; ++c) {
        #pragma unroll
        for (int tl = 0; tl < 4; ++tl) {
            bf16x8 bre = sWv[((0 * 4 + tl) * 4 + c) * 64 + lane];
            bf16x8 bim = sWv[((1 * 4 + tl) * 4 + c) * 64 + lane];
            accRe[tl] = __builtin_amdgcn_mfma_f32_16x16x32_bf16(afrag[c], bre, accRe[tl], 0, 0, 0);
            accIm[tl] = __builtin_amdgcn_mfma_f32_16x16x32_bf16(afrag[c], bim, accIm[tl], 0, 0, 0);
        }
    }

    // epilogue: C/D layout col = lane&15, row = quad*4 + i (m89/m91-verified)
    const int quad = lane >> 4;
    const int col = lane & 15;
    #pragma unroll
    for (int tl = 0; tl < 4; ++tl) {
        int hcol = hs * 64 + tl * 16 + col;
        float lre = lam[hcol];
        float lim = lam[HID + hcol];
        #pragma unroll
        for (int i = 0; i < 4; ++i) {
            int m = m0 + quad * 4 + i;
            size_t off = (size_t)m * HID + hcol;
            float hre = h_re[off];
            float him = h_im[off];
            out[off]                        = lre * hre - lim * him + accRe[tl][i];
            out[(size_t)BATCH * HID + off]  = lre * him + lim * hre + accIm[tl][i];
        }
    }
}

extern "C" void kernel_launch(void* const* d_in, const int* in_sizes, int n_in,
                              void* d_out, int out_size, void* d_ws, size_t ws_size,
                              hipStream_t stream)
{
    const float* inputs    = (const float*)d_in[0];
    const float* h_re      = (const float*)d_in[1];
    const float* h_im      = (const float*)d_in[2];
    const float* nu_log    = (const float*)d_in[3];
    const float* theta_log = (const float*)d_in[4];
    const float* B_real    = (const float*)d_in[5];
    const float* B_img     = (const float*)d_in[6];
    const float* gamma_log = (const float*)d_in[7];

    __bf16* Wfrag = (__bf16*)d_ws;
    float*  lam   = (float*)((char*)d_ws + 131072);

    lru_prep<<<256, 256, 0, stream>>>(nu_log, theta_log, B_real, B_img, gamma_log, Wfrag, lam);

    lru_main<<<(BATCH / 64) * 4, 256, 0, stream>>>(inputs, h_re, h_im, Wfrag, lam, (float*)d_out);
}